// Round 12
// baseline (111.992 us; speedup 1.0000x reference)
//
#include <hip/hip_runtime.h>
#include <stdint.h>

typedef float f32x4 __attribute__((ext_vector_type(4)));
typedef float f32x16 __attribute__((ext_vector_type(16)));
typedef short s16x8 __attribute__((ext_vector_type(8)));
typedef int i32x4 __attribute__((ext_vector_type(4)));

typedef const __attribute__((address_space(1))) uint32_t* gas_t;
typedef __attribute__((address_space(3))) uint32_t* las_t;

__device__ __forceinline__ void gload16(const void* g, void* l) {
  __builtin_amdgcn_global_load_lds((gas_t)g, (las_t)l, 16, 0, 0);
}

__device__ __forceinline__ short f2bf(float f) {
  union { float f; uint32_t u; } v; v.f = f;
  uint32_t r = v.u + 0x7fffu + ((v.u >> 16) & 1u);
  return (short)(r >> 16);
}

__device__ __forceinline__ uint32_t cvtpk_bf16(float lo, float hi) {
  uint32_t r;
  asm("v_cvt_pk_bf16_f32 %0, %1, %2" : "=v"(r) : "v"(lo), "v"(hi));
  return r;
}

// only used with two DISTINCT input values (P-pack path, proven R3-R11)
__device__ __forceinline__ void perm32swap(uint32_t& a, uint32_t& b) {
  asm("v_permlane32_swap_b32 %0, %1" : "+v"(a), "+v"(b));
}

#define MFMA16(a,b,c) __builtin_amdgcn_mfma_f32_16x16x32_bf16((a),(b),(c),0,0,0)
#define MFMA32(a,b,c) __builtin_amdgcn_mfma_f32_32x32x16_bf16((a),(b),(c),0,0,0)

// ============ prep kernel: scan(+detect) | 3x transpose | layernorm =========
__global__ __launch_bounds__(256) void prep_kernel(
    const uint32_t* __restrict__ maskp,
    const float* __restrict__ W_qk, const float* __restrict__ W_v,
    const float* __restrict__ W_out,
    short* __restrict__ WqkT, short* __restrict__ WvT, short* __restrict__ WoutT,
    const float* __restrict__ keys, const float* __restrict__ values,
    const float* __restrict__ g0, const float* __restrict__ b0,
    const float* __restrict__ g1, const float* __restrict__ b1,
    short* __restrict__ kn, short* __restrict__ vn,
    int* __restrict__ idx, int* __restrict__ cnts) {
  __shared__ float tile[32][33];
  __shared__ int wt[4];
  __shared__ int wdet[4];
  const int bid = blockIdx.x, t = threadIdx.x;
  const int lane = t & 63, w = t >> 6;

  if (bid < 2) {
    // ---- scan with inline dtype detect (probe shared first-4KB prefix) ----
    const int b = bid;
    uint4 probe = ((const uint4*)maskp)[t];
    bool big = (probe.x > 1u) || (probe.y > 1u) || (probe.z > 1u) || (probe.w > 1u);
    unsigned long long bal = __ballot(big);
    if (lane == 0) wdet[w] = (bal != 0ull) ? 1 : 0;
    __syncthreads();
    const int f = wdet[0] | wdet[1] | wdet[2] | wdet[3];

    int v[16]; int s = 0;
    if (f) {
      uint4 raw = ((const uint4*)((const uint8_t*)maskp + (size_t)b * 4096))[t];
      uint32_t ws_[4] = {raw.x, raw.y, raw.z, raw.w};
#pragma unroll
      for (int e = 0; e < 16; e++)
        v[e] = (((ws_[e >> 2] >> ((e & 3) * 8)) & 0xffu) == 0) ? 1 : 0;
    } else {
#pragma unroll
      for (int j = 0; j < 4; j++) {
        uint4 raw = ((const uint4*)(maskp + (size_t)b * 4096))[t * 4 + j];
        v[j * 4 + 0] = (raw.x == 0); v[j * 4 + 1] = (raw.y == 0);
        v[j * 4 + 2] = (raw.z == 0); v[j * 4 + 3] = (raw.w == 0);
      }
    }
#pragma unroll
    for (int e = 0; e < 16; e++) s += v[e];
    int sc = s;
#pragma unroll
    for (int off = 1; off < 64; off <<= 1) {
      int y = __shfl_up(sc, off);
      if (lane >= off) sc += y;
    }
    if (lane == 63) wt[w] = sc;
    __syncthreads();
    int woff = 0;
#pragma unroll
    for (int i = 0; i < 4; i++) if (i < w) woff += wt[i];
    int base = woff + sc - s;
#pragma unroll
    for (int e = 0; e < 16; e++)
      if (v[e]) { idx[b * 4096 + base] = b * 4096 + t * 16 + e; base++; }
    const int cnt = wt[0] + wt[1] + wt[2] + wt[3];
    const int cpad = (cnt + 127) & ~127;
    for (int j = cnt + t; j < cpad; j += 256) idx[b * 4096 + j] = 8192;
    if (t == 0) { cnts[b * 2] = cnt; cnts[b * 2 + 1] = cpad; }
  } else if (bid < 1026) {
    // ---- weight transpose f32 -> bf16 (WT[C][R]) ----
    int job = bid - 2;
    const float* W; short* WT; int C;
    if (job < 512)       { W = W_qk;  WT = WqkT;  C = 1024; }
    else if (job < 768)  { job -= 512; W = W_v;   WT = WvT;  C = 512; }
    else                 { job -= 768; W = W_out; WT = WoutT; C = 512; }
    const int tx_ = C >> 5;
    const int c0 = (job % tx_) * 32, r0 = (job / tx_) * 32;
    const int tx = t & 31, ty = t >> 5;
#pragma unroll
    for (int i = 0; i < 32; i += 8)
      tile[ty + i][tx] = W[(size_t)(r0 + ty + i) * C + c0 + tx];
    __syncthreads();
#pragma unroll
    for (int i = 0; i < 32; i += 8)
      WT[(size_t)(c0 + ty + i) * 512 + r0 + tx] = f2bf(tile[tx][ty + i]);
  } else {
    // ---- layernorm f32 -> bf16 (+ sentinel zero row 8192), wave per row ----
    int job = (bid - 1026) * 4 + w;
    if (job >= 16386) return;
    const int sel = job & 1, row = job >> 1;
    short* out = (sel ? vn : kn) + (size_t)row * 512;
    if (row == 8192) {
      s16x8 z = (s16x8){0,0,0,0,0,0,0,0};
      *(s16x8*)(out + lane * 8) = z;
      return;
    }
    const float* x = (sel ? values : keys) + (size_t)row * 512;
    const float* ga = sel ? g1 : g0;
    const float* be = sel ? b1 : b0;
    float4 a = ((const float4*)x)[lane * 2];
    float4 c = ((const float4*)x)[lane * 2 + 1];
    float s = a.x + a.y + a.z + a.w + c.x + c.y + c.z + c.w;
    float sq = a.x*a.x + a.y*a.y + a.z*a.z + a.w*a.w + c.x*c.x + c.y*c.y + c.z*c.z + c.w*c.w;
#pragma unroll
    for (int m = 1; m < 64; m <<= 1) { s += __shfl_xor(s, m); sq += __shfl_xor(sq, m); }
    float mu = s * (1.0f / 512.0f);
    float var = sq * (1.0f / 512.0f) - mu * mu;
    float rs = rsqrtf(var + 1e-5f);
    float xs[8] = {a.x, a.y, a.z, a.w, c.x, c.y, c.z, c.w};
    s16x8 o;
#pragma unroll
    for (int j = 0; j < 8; j++)
      o[j] = f2bf((xs[j] - mu) * rs * ga[lane * 8 + j] + be[lane * 8 + j]);
    *(s16x8*)(out + lane * 8) = o;
  }
}

// ---------------- 128x64 GEMM core, K=512, BK=64 ----------------
__device__ __forceinline__ void gemm_core64(const short* __restrict__ A,
                                            const short* __restrict__ BT,
                                            int row0, int col0,
                                            short* ldsA, short* ldsB,
                                            f32x4 acc[4][2]) {
  const int t = threadIdx.x;
  const int lane = t & 63, w = t >> 6;
  const int wr = w >> 1, wc = w & 1;
  const int l15 = lane & 15, l4 = lane >> 4;
#pragma unroll
  for (int mi = 0; mi < 4; mi++)
#pragma unroll
    for (int ni = 0; ni < 2; ni++) acc[mi][ni] = (f32x4){0.f, 0.f, 0.f, 0.f};

  for (int k0 = 0; k0 < 512; k0 += 64) {
    __syncthreads();
#pragma unroll
    for (int i = 0; i < 4; i++) {
      int q = i * 256 + t;
      int row = q >> 3, ch = q & 7;
      int chs = ch ^ (row & 7);
      gload16(A + (size_t)(row0 + row) * 512 + k0 + chs * 8, ldsA + (i * 256 + w * 64) * 8);
    }
#pragma unroll
    for (int i = 0; i < 2; i++) {
      int q = i * 256 + t;
      int row = q >> 3, ch = q & 7;
      int chs = ch ^ (row & 7);
      gload16(BT + (size_t)(col0 + row) * 512 + k0 + chs * 8, ldsB + (i * 256 + w * 64) * 8);
    }
    __syncthreads();
#pragma unroll
    for (int kk = 0; kk < 2; kk++) {
      s16x8 af[4], bf[2];
#pragma unroll
      for (int mi = 0; mi < 4; mi++) {
        int row = wr * 64 + mi * 16 + l15;
        int ch = (kk * 4 + l4) ^ (row & 7);
        af[mi] = *(const s16x8*)(ldsA + row * 64 + ch * 8);
      }
#pragma unroll
      for (int ni = 0; ni < 2; ni++) {
        int row = wc * 32 + ni * 16 + l15;
        int ch = (kk * 4 + l4) ^ (row & 7);
        bf[ni] = *(const s16x8*)(ldsB + row * 64 + ch * 8);
      }
#pragma unroll
      for (int mi = 0; mi < 4; mi++)
#pragma unroll
        for (int ni = 0; ni < 2; ni++)
          acc[mi][ni] = MFMA16(af[mi], bf[ni], acc[mi][ni]);
    }
  }
}

// idx-gathered 128x128 core (compacted keys; sentinel -> zero row)
__device__ __forceinline__ void gemm_core_idx(const short* __restrict__ A,
                                              const short* __restrict__ BT,
                                              const int* __restrict__ idxp,
                                              int row0, int col0,
                                              short* ldsA, short* ldsB,
                                              f32x4 acc[4][4]) {
  const int t = threadIdx.x;
  const int lane = t & 63, w = t >> 6;
  const int wr = w >> 1, wc = w & 1;
  const int l15 = lane & 15, l4 = lane >> 4;
  int arow[4];
#pragma unroll
  for (int i = 0; i < 4; i++)
    arow[i] = idxp[row0 + ((i * 256 + t) >> 3)];
#pragma unroll
  for (int mi = 0; mi < 4; mi++)
#pragma unroll
    for (int ni = 0; ni < 4; ni++) acc[mi][ni] = (f32x4){0.f, 0.f, 0.f, 0.f};

  for (int k0 = 0; k0 < 512; k0 += 64) {
    __syncthreads();
#pragma unroll
    for (int i = 0; i < 4; i++) {
      int q = i * 256 + t;
      int row = q >> 3, ch = q & 7;
      int chs = ch ^ (row & 7);
      gload16(A + (size_t)arow[i] * 512 + k0 + chs * 8, ldsA + (i * 256 + w * 64) * 8);
      gload16(BT + (size_t)(col0 + row) * 512 + k0 + chs * 8, ldsB + (i * 256 + w * 64) * 8);
    }
    __syncthreads();
#pragma unroll
    for (int kk = 0; kk < 2; kk++) {
      s16x8 af[4], bf[4];
#pragma unroll
      for (int mi = 0; mi < 4; mi++) {
        int row = wr * 64 + mi * 16 + l15;
        int ch = (kk * 4 + l4) ^ (row & 7);
        af[mi] = *(const s16x8*)(ldsA + row * 64 + ch * 8);
      }
#pragma unroll
      for (int ni = 0; ni < 4; ni++) {
        int row = wc * 64 + ni * 16 + l15;
        int ch = (kk * 4 + l4) ^ (row & 7);
        bf[ni] = *(const s16x8*)(ldsB + row * 64 + ch * 8);
      }
#pragma unroll
      for (int mi = 0; mi < 4; mi++)
#pragma unroll
        for (int ni = 0; ni < 4; ni++)
          acc[mi][ni] = MFMA16(af[mi], bf[ni], acc[mi][ni]);
    }
  }
}

// ============ proj kernel: gemm_q (bid<512) | gemm_kv (bid>=512) ============
__global__ __launch_bounds__(256) void proj_kernel(const short* __restrict__ kn,
    const short* __restrict__ vn, const short* __restrict__ WqkT,
    const short* __restrict__ WvT, const int* __restrict__ idx,
    const int* __restrict__ cnts, short* __restrict__ Qg,
    short* __restrict__ Kg, short* __restrict__ VTg) {
  __shared__ short lds[2][128 * 64];
  const int bid = blockIdx.x;
  const int t = threadIdx.x, lane = t & 63, w = t >> 6, wr = w >> 1, wc = w & 1;
  const int l15 = lane & 15, l4 = lane >> 4;

  if (bid < 512) {
    const int bm = bid >> 3, bn = bid & 7;
    f32x4 acc[4][2];
    gemm_core64(kn, WqkT, bm * 128, bn * 64, lds[0], lds[1], acc);
    const float QSCL = 0.125f * 1.44269504088896f;
#pragma unroll
    for (int mi = 0; mi < 4; mi++)
#pragma unroll
      for (int ni = 0; ni < 2; ni++) {
        int c = bn * 64 + wc * 32 + ni * 16 + l15;
        int h = c >> 6, d = c & 63;
#pragma unroll
        for (int r = 0; r < 4; r++) {
          int row = bm * 128 + wr * 64 + mi * 16 + l4 * 4 + r;
          int b = row >> 12, n = row & 4095;
          float v = acc[mi][ni][r];
          v = fminf(fmaxf(v, -5.0f), 5.0f) * QSCL;
          Qg[((size_t)((b * 8 + h) * 4096 + n) << 6) + d] = f2bf(v);
        }
      }
  } else {
    const int b2 = bid - 512;
    const int bm = b2 >> 4, bn = (b2 >> 2) & 3, z = b2 & 3;
    const int b = z & 1, isV = z >> 1;
    if (bm * 128 >= cnts[b * 2 + 1]) return;
    f32x4 acc[4][4];
    if (!isV) {
      gemm_core_idx(kn, WqkT, idx + b * 4096, bm * 128, 512 + bn * 128, lds[0], lds[1], acc);
#pragma unroll
      for (int mi = 0; mi < 4; mi++)
#pragma unroll
        for (int ni = 0; ni < 4; ni++) {
          int c = bn * 128 + wc * 64 + ni * 16 + l15;
          int h = c >> 6, d = c & 63;
#pragma unroll
          for (int r = 0; r < 4; r++) {
            int j = bm * 128 + wr * 64 + mi * 16 + l4 * 4 + r;
            float v = acc[mi][ni][r];
            v = fminf(fmaxf(v, -5.0f), 5.0f);
            Kg[((size_t)((b * 8 + h) * 4096 + j) << 6) + d] = f2bf(v);
          }
        }
    } else {
      gemm_core_idx(vn, WvT, idx + b * 4096, bm * 128, bn * 128, lds[0], lds[1], acc);
      __syncthreads();
      short* T = (short*)lds;
#pragma unroll
      for (int mi = 0; mi < 4; mi++)
#pragma unroll
        for (int ni = 0; ni < 4; ni++) {
          int c_loc = wc * 64 + ni * 16 + l15;
#pragma unroll
          for (int r = 0; r < 4; r++) {
            int n_loc = wr * 64 + mi * 16 + l4 * 4 + r;
            T[c_loc * 128 + (((n_loc >> 3) ^ (c_loc & 15)) << 3) + (n_loc & 7)] = f2bf(acc[mi][ni][r]);
          }
        }
      __syncthreads();
#pragma unroll
      for (int jj = 0; jj < 8; jj++) {
        int c_loc = jj * 16 + (t >> 4);
        int nch = t & 15;
        s16x8 v = *(const s16x8*)(T + c_loc * 128 + ((nch ^ (c_loc & 15)) << 3));
        int cg = bn * 128 + c_loc, h = cg >> 6, d = cg & 63;
        int j = bm * 128 + nch * 8;
        *(s16x8*)(VTg + (size_t)((b * 8 + h) * 64 + d) * 4096 + j) = v;
      }
    }
  }
}

// GEMM-out (128x64 tiles): O @ W_out + b -> f32
__global__ __launch_bounds__(256) void gemm_out_kernel(const short* __restrict__ O,
    const short* __restrict__ WoutT, const float* __restrict__ bias, float* __restrict__ out) {
  __shared__ short ldsA[128 * 64], ldsB[64 * 64];
  f32x4 acc[4][2];
  const int bm = blockIdx.x, bn = blockIdx.y;
  gemm_core64(O, WoutT, bm * 128, bn * 64, ldsA, ldsB, acc);
  const int t = threadIdx.x, lane = t & 63, w = t >> 6, wr = w >> 1, wc = w & 1;
  const int l15 = lane & 15, l4 = lane >> 4;
#pragma unroll
  for (int ni = 0; ni < 2; ni++) {
    int col = bn * 64 + wc * 32 + ni * 16 + l15;
    float bv = bias[col];
#pragma unroll
    for (int mi = 0; mi < 4; mi++)
#pragma unroll
      for (int r = 0; r < 4; r++) {
        int row = bm * 128 + wr * 64 + mi * 16 + l4 * 4 + r;
        out[(size_t)row * 512 + col] = acc[mi][ni][r] + bv;
      }
  }
}

// ---------------- flash attention (R12: STATIC-MAX softmax) -----------------
// Softmax is shift-invariant; with clipped Q/K the log2-domain scores are
// bounded (|S|<~3 actual, 288 theoretical vs exp2 overflow at 128+M). Using a
// fixed M=4 (folded into the MFMA accumulator init, inline const -4.0):
//   - no max scan, no shfl, no defer branch, no subtract pass
//   - both K-halves share the scale -> merge is a plain (O,l) add
__global__ __launch_bounds__(512, 4) void attn_kernel(const short* __restrict__ Qg,
    const short* __restrict__ Kg, const short* __restrict__ VTg,
    const int* __restrict__ cnts, short* __restrict__ O) {
  __shared__ short smem[32768];   // 64 KB
  short* KloB = smem;
  short* VloB = smem + 8192;
  short* KhiB = smem + 16384;
  short* VhiB = smem + 24576;

  const int bid = blockIdx.x;
  const int xcd = bid & 7, local = bid >> 3;
  const int bh = xcd * 2 + (local & 1);
  const int qb = local >> 1;
  const int b = bh >> 3, h = bh & 7;
  const int t = threadIdx.x, lane = t & 63, w = t >> 6;
  const int l31 = lane & 31, hh = lane >> 5;
  const int half = w >> 2, wq = w & 3;

  const short* Qp = Qg + (size_t)bh * 4096 * 64;
  const short* Kp = Kg + (size_t)bh * 4096 * 64;
  const short* Vp = VTg + (size_t)bh * 64 * 4096;

  const int cnt  = cnts[b * 2];
  const int cpad = cnts[b * 2 + 1];
  const int nit  = cpad >> 7;
  const int hb   = cpad >> 1;
  const int kbase = half ? hb : 0;

  const int qrow = qb * 128 + wq * 32 + l31;
  s16x8 qf[4];
#pragma unroll
  for (int dblk = 0; dblk < 4; dblk++)
    qf[dblk] = *(const s16x8*)(Qp + (size_t)qrow * 64 + dblk * 16 + hh * 8);

  f32x16 oac[2];
#pragma unroll
  for (int db = 0; db < 2; db++)
#pragma unroll
    for (int r = 0; r < 16; r++) oac[db][r] = 0.0f;
  float l_ = 0.0f;

  const short* KtS = half ? KhiB : KloB;
  const short* VtS = half ? VhiB : VloB;

  auto STAGE = [&](int buf, int i) {
    int row = t >> 3, ch = t & 7, chs = ch ^ (row & 7);
    gload16(Kp + (size_t)(i * 64 + row) * 64 + chs * 8,        KloB + buf * 4096 + w * 512);
    gload16(Kp + (size_t)(hb + i * 64 + row) * 64 + chs * 8,   KhiB + buf * 4096 + w * 512);
    gload16(Vp + (size_t)row * 4096 + i * 64 + chs * 8,        VloB + buf * 4096 + w * 512);
    gload16(Vp + (size_t)row * 4096 + hb + i * 64 + chs * 8,   VhiB + buf * 4096 + w * 512);
  };

  STAGE(0, 0);
  __syncthreads();

  for (int it = 0; it < nit; it++) {
    const int cur = it & 1;
    if (it < nit - 1) STAGE(cur ^ 1, it + 1);
    const short* Kt = KtS + cur * 4096;
    const int kb_t = kbase + it * 64;

    // S - M directly out of MFMA: acc initialized to -4.0 (inline const)
    f32x16 sc[2];
    __builtin_amdgcn_s_setprio(1);
#pragma unroll
    for (int kb = 0; kb < 2; kb++) {
      f32x16 s_;
#pragma unroll
      for (int r = 0; r < 16; r++) s_[r] = -4.0f;
      const int krow = kb * 32 + l31;
#pragma unroll
      for (int dblk = 0; dblk < 4; dblk++) {
        int ch = (2 * dblk + hh) ^ (krow & 7);
        s16x8 kf = *(const s16x8*)(Kt + krow * 64 + ch * 8);
        s_ = MFMA32(kf, qf[dblk], s_);
      }
      sc[kb] = s_;
    }
    __builtin_amdgcn_s_setprio(0);

    // boundary tile: dummy keys (>= cnt) -> exp2(-1e30) == 0 exactly
    if (kb_t + 64 > cnt) {
#pragma unroll
      for (int kb = 0; kb < 2; kb++)
#pragma unroll
        for (int r = 0; r < 16; r++) {
          int key = kb_t + kb * 32 + (r & 3) + 8 * (r >> 2) + 4 * hh;
          if (key >= cnt) sc[kb][r] = -1e30f;
        }
    }

    // P = exp2(S - M); pack to bf16 A-layout via cvt_pk + permlane32_swap
    float ls = 0.0f;
    uint32_t pw[4][4];
#pragma unroll
    for (int kb = 0; kb < 2; kb++) {
      float p[16];
#pragma unroll
      for (int r = 0; r < 16; r++) {
        p[r] = __builtin_amdgcn_exp2f(sc[kb][r]);
        ls += p[r];
      }
#pragma unroll
      for (int ksl = 0; ksl < 2; ksl++) {
        const int fi = kb * 2 + ksl, b0 = ksl * 8;
        uint32_t a0 = cvtpk_bf16(p[b0 + 0], p[b0 + 1]);
        uint32_t b0w = cvtpk_bf16(p[b0 + 4], p[b0 + 5]);
        perm32swap(a0, b0w);
        uint32_t a1 = cvtpk_bf16(p[b0 + 2], p[b0 + 3]);
        uint32_t b1w = cvtpk_bf16(p[b0 + 6], p[b0 + 7]);
        perm32swap(a1, b1w);
        pw[fi][0] = a0; pw[fi][1] = a1; pw[fi][2] = b0w; pw[fi][3] = b1w;
      }
    }
    ls += __shfl_xor(ls, 32);
    l_ += ls;

    // O^T += V^T . P^T
    __builtin_amdgcn_s_setprio(1);
#pragma unroll
    for (int db = 0; db < 2; db++) {
      const int d = db * 32 + l31;
#pragma unroll
      for (int ks = 0; ks < 4; ks++) {
        int ch = (2 * ks + hh) ^ (d & 7);
        s16x8 vf = *(const s16x8*)(VtS + cur * 4096 + d * 64 + ch * 8);
        i32x4 pv = {(int)pw[ks][0], (int)pw[ks][1], (int)pw[ks][2], (int)pw[ks][3]};
        oac[db] = MFMA32(vf, __builtin_bit_cast(s16x8, pv), oac[db]);
      }
    }
    __builtin_amdgcn_s_setprio(0);

    __syncthreads();
  }

  // ---- merge of the two K-halves: plain (O, l) add (shared static scale) ----
  float* mrg = (float*)smem;          // [4 waves][32][64] f32 = 32KB
  float* ml  = mrg + 8192;            // [4 waves][64] l = 1KB
  if (half) {
#pragma unroll
    for (int db = 0; db < 2; db++)
#pragma unroll
      for (int r = 0; r < 16; r++)
        mrg[wq * 2048 + (db * 16 + r) * 64 + lane] = oac[db][r];
    ml[wq * 64 + lane] = l_;
  }
  __syncthreads();
  if (!half) {
    l_ += ml[wq * 64 + lane];
#pragma unroll
    for (int db = 0; db < 2; db++)
#pragma unroll
      for (int r = 0; r < 16; r++)
        oac[db][r] += mrg[wq * 2048 + (db * 16 + r) * 64 + lane];

    // epilogue: normalize, transpose via per-wave LDS region, coalesced store
    float inv = 1.0f / l_;
    short* epi = smem + 17408 + wq * 2048;
#pragma unroll
    for (int db = 0; db < 2; db++)
#pragma unroll
      for (int g = 0; g < 4; g++) {
        uint32_t w0 = cvtpk_bf16(oac[db][g * 4 + 0] * inv, oac[db][g * 4 + 1] * inv);
        uint32_t w1 = cvtpk_bf16(oac[db][g * 4 + 2] * inv, oac[db][g * 4 + 3] * inv);
        int chunk = db * 4 + g;
        uint2* dst = (uint2*)((char*)epi + l31 * 128 + ((chunk ^ (l31 & 7)) << 4) + hh * 8);
        *dst = make_uint2(w0, w1);
      }
#pragma unroll
    for (int i = 0; i < 4; i++) {
      int c = hh * 4 + i;
      s16x8 v = *(const s16x8*)((char*)epi + l31 * 128 + ((c ^ (l31 & 7)) << 4));
      *(s16x8*)(O + ((size_t)(b * 4096 + qrow) * 512) + h * 64 + c * 8) = v;
    }
  }
}

extern "C" void kernel_launch(void* const* d_in, const int* in_sizes, int n_in,
                              void* d_out, int out_size, void* d_ws, size_t ws_size,
                              hipStream_t stream) {
  const float* keys     = (const float*)d_in[0];
  const float* values   = (const float*)d_in[1];
  const uint32_t* maskp = (const uint32_t*)d_in[2];
  const float* qk_gamma = (const float*)d_in[3];
  const float* qk_beta  = (const float*)d_in[4];
  const float* v_gamma  = (const float*)d_in[5];
  const float* v_beta   = (const float*)d_in[6];
  const float* W_qk     = (const float*)d_in[7];
  const float* W_v      = (const float*)d_in[8];
  const float* W_out    = (const float*)d_in[9];
  const float* b_out    = (const float*)d_in[10];
  float* out = (float*)d_out;
  char* ws = (char*)d_ws;
  const size_t MB = 1u << 20;
  short* kn    = (short*)(ws);                     // 8193 rows x 512 bf16
  short* vn    = (short*)(ws + 9 * MB);
  short* Qg    = (short*)(ws + 18 * MB);
  short* Kg    = (short*)(ws + 26 * MB);
  short* VTg   = (short*)(ws + 34 * MB);
  short* O     = (short*)(ws + 42 * MB);
  short* WqkT  = (short*)(ws + 50 * MB);
  short* WvT   = (short*)(ws + 51 * MB);
  short* WoutT = (short*)(ws + 51 * MB + 512 * 1024);
  int*   idx   = (int*)(ws + 52 * MB);
  int*   cnts  = (int*)(ws + 52 * MB + 32 * 1024);

  prep_kernel<<<5123, 256, 0, stream>>>(maskp, W_qk, W_v, W_out, WqkT, WvT, WoutT,
                                        keys, values, qk_gamma, qk_beta, v_gamma, v_beta,
                                        kn, vn, idx, cnts);
  proj_kernel<<<1024, 256, 0, stream>>>(kn, vn, WqkT, WvT, idx, cnts, Qg, Kg, VTg);
  attn_kernel<<<512, 512, 0, stream>>>(Qg, Kg, VTg, cnts, O);
  gemm_out_kernel<<<dim3(64, 8), 256, 0, stream>>>(O, WoutT, b_out, out);
}

// Round 13
// 95.530 us; speedup vs baseline: 1.1723x; 1.1723x over previous
//
#include <hip/hip_runtime.h>
#include <stdint.h>

typedef float f32x4 __attribute__((ext_vector_type(4)));
typedef float f32x16 __attribute__((ext_vector_type(16)));
typedef short s16x8 __attribute__((ext_vector_type(8)));
typedef int i32x4 __attribute__((ext_vector_type(4)));

typedef const __attribute__((address_space(1))) uint32_t* gas_t;
typedef __attribute__((address_space(3))) uint32_t* las_t;

__device__ __forceinline__ void gload16(const void* g, void* l) {
  __builtin_amdgcn_global_load_lds((gas_t)g, (las_t)l, 16, 0, 0);
}

__device__ __forceinline__ short f2bf(float f) {
  union { float f; uint32_t u; } v; v.f = f;
  uint32_t r = v.u + 0x7fffu + ((v.u >> 16) & 1u);
  return (short)(r >> 16);
}

__device__ __forceinline__ uint32_t cvtpk_bf16(float lo, float hi) {
  uint32_t r;
  asm("v_cvt_pk_bf16_f32 %0, %1, %2" : "=v"(r) : "v"(lo), "v"(hi));
  return r;
}

// only used with two DISTINCT input values (P-pack path, proven R3-R11)
__device__ __forceinline__ void perm32swap(uint32_t& a, uint32_t& b) {
  asm("v_permlane32_swap_b32 %0, %1" : "+v"(a), "+v"(b));
}

#define MFMA16(a,b,c) __builtin_amdgcn_mfma_f32_16x16x32_bf16((a),(b),(c),0,0,0)
#define MFMA32(a,b,c) __builtin_amdgcn_mfma_f32_32x32x16_bf16((a),(b),(c),0,0,0)

// ============ prep kernel: scan(+detect) | 3x transpose | layernorm =========
__global__ __launch_bounds__(256) void prep_kernel(
    const uint32_t* __restrict__ maskp,
    const float* __restrict__ W_qk, const float* __restrict__ W_v,
    const float* __restrict__ W_out,
    short* __restrict__ WqkT, short* __restrict__ WvT, short* __restrict__ WoutT,
    const float* __restrict__ keys, const float* __restrict__ values,
    const float* __restrict__ g0, const float* __restrict__ b0,
    const float* __restrict__ g1, const float* __restrict__ b1,
    short* __restrict__ kn, short* __restrict__ vn,
    int* __restrict__ idx, int* __restrict__ cnts) {
  __shared__ float tile[32][33];
  __shared__ int wt[4];
  __shared__ int wdet[4];
  const int bid = blockIdx.x, t = threadIdx.x;
  const int lane = t & 63, w = t >> 6;

  if (bid < 2) {
    // ---- scan with inline dtype detect (probe shared first-4KB prefix) ----
    const int b = bid;
    uint4 probe = ((const uint4*)maskp)[t];
    bool big = (probe.x > 1u) || (probe.y > 1u) || (probe.z > 1u) || (probe.w > 1u);
    unsigned long long bal = __ballot(big);
    if (lane == 0) wdet[w] = (bal != 0ull) ? 1 : 0;
    __syncthreads();
    const int f = wdet[0] | wdet[1] | wdet[2] | wdet[3];

    int v[16]; int s = 0;
    if (f) {
      uint4 raw = ((const uint4*)((const uint8_t*)maskp + (size_t)b * 4096))[t];
      uint32_t ws_[4] = {raw.x, raw.y, raw.z, raw.w};
#pragma unroll
      for (int e = 0; e < 16; e++)
        v[e] = (((ws_[e >> 2] >> ((e & 3) * 8)) & 0xffu) == 0) ? 1 : 0;
    } else {
#pragma unroll
      for (int j = 0; j < 4; j++) {
        uint4 raw = ((const uint4*)(maskp + (size_t)b * 4096))[t * 4 + j];
        v[j * 4 + 0] = (raw.x == 0); v[j * 4 + 1] = (raw.y == 0);
        v[j * 4 + 2] = (raw.z == 0); v[j * 4 + 3] = (raw.w == 0);
      }
    }
#pragma unroll
    for (int e = 0; e < 16; e++) s += v[e];
    int sc = s;
#pragma unroll
    for (int off = 1; off < 64; off <<= 1) {
      int y = __shfl_up(sc, off);
      if (lane >= off) sc += y;
    }
    if (lane == 63) wt[w] = sc;
    __syncthreads();
    int woff = 0;
#pragma unroll
    for (int i = 0; i < 4; i++) if (i < w) woff += wt[i];
    int base = woff + sc - s;
#pragma unroll
    for (int e = 0; e < 16; e++)
      if (v[e]) { idx[b * 4096 + base] = b * 4096 + t * 16 + e; base++; }
    const int cnt = wt[0] + wt[1] + wt[2] + wt[3];
    const int cpad = (cnt + 127) & ~127;
    for (int j = cnt + t; j < cpad; j += 256) idx[b * 4096 + j] = 8192;
    if (t == 0) { cnts[b * 2] = cnt; cnts[b * 2 + 1] = cpad; }
  } else if (bid < 1026) {
    // ---- weight transpose f32 -> bf16 (WT[C][R]) ----
    int job = bid - 2;
    const float* W; short* WT; int C;
    if (job < 512)       { W = W_qk;  WT = WqkT;  C = 1024; }
    else if (job < 768)  { job -= 512; W = W_v;   WT = WvT;  C = 512; }
    else                 { job -= 768; W = W_out; WT = WoutT; C = 512; }
    const int tx_ = C >> 5;
    const int c0 = (job % tx_) * 32, r0 = (job / tx_) * 32;
    const int tx = t & 31, ty = t >> 5;
#pragma unroll
    for (int i = 0; i < 32; i += 8)
      tile[ty + i][tx] = W[(size_t)(r0 + ty + i) * C + c0 + tx];
    __syncthreads();
#pragma unroll
    for (int i = 0; i < 32; i += 8)
      WT[(size_t)(c0 + ty + i) * 512 + r0 + tx] = f2bf(tile[tx][ty + i]);
  } else {
    // ---- layernorm f32 -> bf16 (+ sentinel zero row 8192), wave per row ----
    int job = (bid - 1026) * 4 + w;
    if (job >= 16386) return;
    const int sel = job & 1, row = job >> 1;
    short* out = (sel ? vn : kn) + (size_t)row * 512;
    if (row == 8192) {
      s16x8 z = (s16x8){0,0,0,0,0,0,0,0};
      *(s16x8*)(out + lane * 8) = z;
      return;
    }
    const float* x = (sel ? values : keys) + (size_t)row * 512;
    const float* ga = sel ? g1 : g0;
    const float* be = sel ? b1 : b0;
    float4 a = ((const float4*)x)[lane * 2];
    float4 c = ((const float4*)x)[lane * 2 + 1];
    float s = a.x + a.y + a.z + a.w + c.x + c.y + c.z + c.w;
    float sq = a.x*a.x + a.y*a.y + a.z*a.z + a.w*a.w + c.x*c.x + c.y*c.y + c.z*c.z + c.w*c.w;
#pragma unroll
    for (int m = 1; m < 64; m <<= 1) { s += __shfl_xor(s, m); sq += __shfl_xor(sq, m); }
    float mu = s * (1.0f / 512.0f);
    float var = sq * (1.0f / 512.0f) - mu * mu;
    float rs = rsqrtf(var + 1e-5f);
    float xs[8] = {a.x, a.y, a.z, a.w, c.x, c.y, c.z, c.w};
    s16x8 o;
#pragma unroll
    for (int j = 0; j < 8; j++)
      o[j] = f2bf((xs[j] - mu) * rs * ga[lane * 8 + j] + be[lane * 8 + j]);
    *(s16x8*)(out + lane * 8) = o;
  }
}

// ---------------- 128x64 GEMM core, K=512, BK=64 ----------------
__device__ __forceinline__ void gemm_core64(const short* __restrict__ A,
                                            const short* __restrict__ BT,
                                            int row0, int col0,
                                            short* ldsA, short* ldsB,
                                            f32x4 acc[4][2]) {
  const int t = threadIdx.x;
  const int lane = t & 63, w = t >> 6;
  const int wr = w >> 1, wc = w & 1;
  const int l15 = lane & 15, l4 = lane >> 4;
#pragma unroll
  for (int mi = 0; mi < 4; mi++)
#pragma unroll
    for (int ni = 0; ni < 2; ni++) acc[mi][ni] = (f32x4){0.f, 0.f, 0.f, 0.f};

  for (int k0 = 0; k0 < 512; k0 += 64) {
    __syncthreads();
#pragma unroll
    for (int i = 0; i < 4; i++) {
      int q = i * 256 + t;
      int row = q >> 3, ch = q & 7;
      int chs = ch ^ (row & 7);
      gload16(A + (size_t)(row0 + row) * 512 + k0 + chs * 8, ldsA + (i * 256 + w * 64) * 8);
    }
#pragma unroll
    for (int i = 0; i < 2; i++) {
      int q = i * 256 + t;
      int row = q >> 3, ch = q & 7;
      int chs = ch ^ (row & 7);
      gload16(BT + (size_t)(col0 + row) * 512 + k0 + chs * 8, ldsB + (i * 256 + w * 64) * 8);
    }
    __syncthreads();
#pragma unroll
    for (int kk = 0; kk < 2; kk++) {
      s16x8 af[4], bf[2];
#pragma unroll
      for (int mi = 0; mi < 4; mi++) {
        int row = wr * 64 + mi * 16 + l15;
        int ch = (kk * 4 + l4) ^ (row & 7);
        af[mi] = *(const s16x8*)(ldsA + row * 64 + ch * 8);
      }
#pragma unroll
      for (int ni = 0; ni < 2; ni++) {
        int row = wc * 32 + ni * 16 + l15;
        int ch = (kk * 4 + l4) ^ (row & 7);
        bf[ni] = *(const s16x8*)(ldsB + row * 64 + ch * 8);
      }
#pragma unroll
      for (int mi = 0; mi < 4; mi++)
#pragma unroll
        for (int ni = 0; ni < 2; ni++)
          acc[mi][ni] = MFMA16(af[mi], bf[ni], acc[mi][ni]);
    }
  }
}

// idx-gathered 128x128 core (compacted keys; sentinel -> zero row)
__device__ __forceinline__ void gemm_core_idx(const short* __restrict__ A,
                                              const short* __restrict__ BT,
                                              const int* __restrict__ idxp,
                                              int row0, int col0,
                                              short* ldsA, short* ldsB,
                                              f32x4 acc[4][4]) {
  const int t = threadIdx.x;
  const int lane = t & 63, w = t >> 6;
  const int wr = w >> 1, wc = w & 1;
  const int l15 = lane & 15, l4 = lane >> 4;
  int arow[4];
#pragma unroll
  for (int i = 0; i < 4; i++)
    arow[i] = idxp[row0 + ((i * 256 + t) >> 3)];
#pragma unroll
  for (int mi = 0; mi < 4; mi++)
#pragma unroll
    for (int ni = 0; ni < 4; ni++) acc[mi][ni] = (f32x4){0.f, 0.f, 0.f, 0.f};

  for (int k0 = 0; k0 < 512; k0 += 64) {
    __syncthreads();
#pragma unroll
    for (int i = 0; i < 4; i++) {
      int q = i * 256 + t;
      int row = q >> 3, ch = q & 7;
      int chs = ch ^ (row & 7);
      gload16(A + (size_t)arow[i] * 512 + k0 + chs * 8, ldsA + (i * 256 + w * 64) * 8);
      gload16(BT + (size_t)(col0 + row) * 512 + k0 + chs * 8, ldsB + (i * 256 + w * 64) * 8);
    }
    __syncthreads();
#pragma unroll
    for (int kk = 0; kk < 2; kk++) {
      s16x8 af[4], bf[4];
#pragma unroll
      for (int mi = 0; mi < 4; mi++) {
        int row = wr * 64 + mi * 16 + l15;
        int ch = (kk * 4 + l4) ^ (row & 7);
        af[mi] = *(const s16x8*)(ldsA + row * 64 + ch * 8);
      }
#pragma unroll
      for (int ni = 0; ni < 4; ni++) {
        int row = wc * 64 + ni * 16 + l15;
        int ch = (kk * 4 + l4) ^ (row & 7);
        bf[ni] = *(const s16x8*)(ldsB + row * 64 + ch * 8);
      }
#pragma unroll
      for (int mi = 0; mi < 4; mi++)
#pragma unroll
        for (int ni = 0; ni < 4; ni++)
          acc[mi][ni] = MFMA16(af[mi], bf[ni], acc[mi][ni]);
    }
  }
}

// ============ proj kernel: gemm_q (bid<512) | gemm_kv (bid>=512) ============
__global__ __launch_bounds__(256) void proj_kernel(const short* __restrict__ kn,
    const short* __restrict__ vn, const short* __restrict__ WqkT,
    const short* __restrict__ WvT, const int* __restrict__ idx,
    const int* __restrict__ cnts, short* __restrict__ Qg,
    short* __restrict__ Kg, short* __restrict__ VTg) {
  __shared__ short lds[2][128 * 64];
  const int bid = blockIdx.x;
  const int t = threadIdx.x, lane = t & 63, w = t >> 6, wr = w >> 1, wc = w & 1;
  const int l15 = lane & 15, l4 = lane >> 4;

  if (bid < 512) {
    const int bm = bid >> 3, bn = bid & 7;
    f32x4 acc[4][2];
    gemm_core64(kn, WqkT, bm * 128, bn * 64, lds[0], lds[1], acc);
    const float QSCL = 0.125f * 1.44269504088896f;
#pragma unroll
    for (int mi = 0; mi < 4; mi++)
#pragma unroll
      for (int ni = 0; ni < 2; ni++) {
        int c = bn * 64 + wc * 32 + ni * 16 + l15;
        int h = c >> 6, d = c & 63;
#pragma unroll
        for (int r = 0; r < 4; r++) {
          int row = bm * 128 + wr * 64 + mi * 16 + l4 * 4 + r;
          int b = row >> 12, n = row & 4095;
          float v = acc[mi][ni][r];
          v = fminf(fmaxf(v, -5.0f), 5.0f) * QSCL;
          Qg[((size_t)((b * 8 + h) * 4096 + n) << 6) + d] = f2bf(v);
        }
      }
  } else {
    const int b2 = bid - 512;
    const int bm = b2 >> 4, bn = (b2 >> 2) & 3, z = b2 & 3;
    const int b = z & 1, isV = z >> 1;
    if (bm * 128 >= cnts[b * 2 + 1]) return;
    f32x4 acc[4][4];
    if (!isV) {
      gemm_core_idx(kn, WqkT, idx + b * 4096, bm * 128, 512 + bn * 128, lds[0], lds[1], acc);
#pragma unroll
      for (int mi = 0; mi < 4; mi++)
#pragma unroll
        for (int ni = 0; ni < 4; ni++) {
          int c = bn * 128 + wc * 64 + ni * 16 + l15;
          int h = c >> 6, d = c & 63;
#pragma unroll
          for (int r = 0; r < 4; r++) {
            int j = bm * 128 + wr * 64 + mi * 16 + l4 * 4 + r;
            float v = acc[mi][ni][r];
            v = fminf(fmaxf(v, -5.0f), 5.0f);
            Kg[((size_t)((b * 8 + h) * 4096 + j) << 6) + d] = f2bf(v);
          }
        }
    } else {
      gemm_core_idx(vn, WvT, idx + b * 4096, bm * 128, bn * 128, lds[0], lds[1], acc);
      __syncthreads();
      short* T = (short*)lds;
#pragma unroll
      for (int mi = 0; mi < 4; mi++)
#pragma unroll
        for (int ni = 0; ni < 4; ni++) {
          int c_loc = wc * 64 + ni * 16 + l15;
#pragma unroll
          for (int r = 0; r < 4; r++) {
            int n_loc = wr * 64 + mi * 16 + l4 * 4 + r;
            T[c_loc * 128 + (((n_loc >> 3) ^ (c_loc & 15)) << 3) + (n_loc & 7)] = f2bf(acc[mi][ni][r]);
          }
        }
      __syncthreads();
#pragma unroll
      for (int jj = 0; jj < 8; jj++) {
        int c_loc = jj * 16 + (t >> 4);
        int nch = t & 15;
        s16x8 v = *(const s16x8*)(T + c_loc * 128 + ((nch ^ (c_loc & 15)) << 3));
        int cg = bn * 128 + c_loc, h = cg >> 6, d = cg & 63;
        int j = bm * 128 + nch * 8;
        *(s16x8*)(VTg + (size_t)((b * 8 + h) * 64 + d) * 4096 + j) = v;
      }
    }
  }
}

// GEMM-out (128x64 tiles): O @ W_out + b -> f32
__global__ __launch_bounds__(256) void gemm_out_kernel(const short* __restrict__ O,
    const short* __restrict__ WoutT, const float* __restrict__ bias, float* __restrict__ out) {
  __shared__ short ldsA[128 * 64], ldsB[64 * 64];
  f32x4 acc[4][2];
  const int bm = blockIdx.x, bn = blockIdx.y;
  gemm_core64(O, WoutT, bm * 128, bn * 64, ldsA, ldsB, acc);
  const int t = threadIdx.x, lane = t & 63, w = t >> 6, wr = w >> 1, wc = w & 1;
  const int l15 = lane & 15, l4 = lane >> 4;
#pragma unroll
  for (int ni = 0; ni < 2; ni++) {
    int col = bn * 64 + wc * 32 + ni * 16 + l15;
    float bv = bias[col];
#pragma unroll
    for (int mi = 0; mi < 4; mi++)
#pragma unroll
      for (int r = 0; r < 4; r++) {
        int row = bm * 128 + wr * 64 + mi * 16 + l4 * 4 + r;
        out[(size_t)row * 512 + col] = acc[mi][ni][r] + bv;
      }
  }
}

// ---------------- flash attention (R13: R11-proven, + 4-way ls tree) --------
__global__ __launch_bounds__(512, 4) void attn_kernel(const short* __restrict__ Qg,
    const short* __restrict__ Kg, const short* __restrict__ VTg,
    const int* __restrict__ cnts, short* __restrict__ O) {
  __shared__ short smem[32768];
  short* KloB = smem;
  short* VloB = smem + 8192;
  short* KhiB = smem + 16384;
  short* VhiB = smem + 24576;

  const int bid = blockIdx.x;
  const int xcd = bid & 7, local = bid >> 3;
  const int bh = xcd * 2 + (local & 1);
  const int qb = local >> 1;
  const int b = bh >> 3, h = bh & 7;
  const int t = threadIdx.x, lane = t & 63, w = t >> 6;
  const int l31 = lane & 31, hh = lane >> 5;
  const int half = w >> 2, wq = w & 3;

  const short* Qp = Qg + (size_t)bh * 4096 * 64;
  const short* Kp = Kg + (size_t)bh * 4096 * 64;
  const short* Vp = VTg + (size_t)bh * 64 * 4096;

  const int cnt  = cnts[b * 2];
  const int cpad = cnts[b * 2 + 1];
  const int nit  = cpad >> 7;
  const int hb   = cpad >> 1;
  const int kbase = half ? hb : 0;

  const int qrow = qb * 128 + wq * 32 + l31;
  s16x8 qf[4];
#pragma unroll
  for (int dblk = 0; dblk < 4; dblk++)
    qf[dblk] = *(const s16x8*)(Qp + (size_t)qrow * 64 + dblk * 16 + hh * 8);

  f32x16 oac[2];
#pragma unroll
  for (int db = 0; db < 2; db++)
#pragma unroll
    for (int r = 0; r < 16; r++) oac[db][r] = 0.0f;
  float m_ = -60.0f, l_ = 0.0f;

  const short* KtS = half ? KhiB : KloB;
  const short* VtS = half ? VhiB : VloB;

  auto STAGE = [&](int buf, int i) {
    int row = t >> 3, ch = t & 7, chs = ch ^ (row & 7);
    gload16(Kp + (size_t)(i * 64 + row) * 64 + chs * 8,        KloB + buf * 4096 + w * 512);
    gload16(Kp + (size_t)(hb + i * 64 + row) * 64 + chs * 8,   KhiB + buf * 4096 + w * 512);
    gload16(Vp + (size_t)row * 4096 + i * 64 + chs * 8,        VloB + buf * 4096 + w * 512);
    gload16(Vp + (size_t)row * 4096 + hb + i * 64 + chs * 8,   VhiB + buf * 4096 + w * 512);
  };

  STAGE(0, 0);
  __syncthreads();

  for (int it = 0; it < nit; it++) {
    const int cur = it & 1;
    if (it < nit - 1) STAGE(cur ^ 1, it + 1);
    const short* Kt = KtS + cur * 4096;
    const int kb_t = kbase + it * 64;

    f32x16 sc[2];
    __builtin_amdgcn_s_setprio(1);
#pragma unroll
    for (int kb = 0; kb < 2; kb++) {
      f32x16 s_;
#pragma unroll
      for (int r = 0; r < 16; r++) s_[r] = 0.0f;
      const int krow = kb * 32 + l31;
#pragma unroll
      for (int dblk = 0; dblk < 4; dblk++) {
        int ch = (2 * dblk + hh) ^ (krow & 7);
        s16x8 kf = *(const s16x8*)(Kt + krow * 64 + ch * 8);
        s_ = MFMA32(kf, qf[dblk], s_);
      }
      sc[kb] = s_;
    }
    __builtin_amdgcn_s_setprio(0);

    if (kb_t + 64 > cnt) {
#pragma unroll
      for (int kb = 0; kb < 2; kb++)
#pragma unroll
        for (int r = 0; r < 16; r++) {
          int key = kb_t + kb * 32 + (r & 3) + 8 * (r >> 2) + 4 * hh;
          if (key >= cnt) sc[kb][r] = -1e30f;
        }
    }

    float mx0 = -1e30f, mx1 = -1e30f, mx2 = -1e30f, mx3 = -1e30f;
#pragma unroll
    for (int kb = 0; kb < 2; kb++)
#pragma unroll
      for (int r = 0; r < 16; r += 4) {
        mx0 = fmaxf(mx0, sc[kb][r + 0]);
        mx1 = fmaxf(mx1, sc[kb][r + 1]);
        mx2 = fmaxf(mx2, sc[kb][r + 2]);
        mx3 = fmaxf(mx3, sc[kb][r + 3]);
      }
    float mx = fmaxf(fmaxf(mx0, mx1), fmaxf(mx2, mx3));
    mx = fmaxf(mx, __shfl_xor(mx, 32));

    if (!__all(mx <= m_ + 5.0f)) {
      float mnew = fmaxf(m_, mx);
      float alpha = __builtin_amdgcn_exp2f(m_ - mnew);
      m_ = mnew;
      l_ *= alpha;
#pragma unroll
      for (int db = 0; db < 2; db++)
#pragma unroll
        for (int r = 0; r < 16; r++) oac[db][r] *= alpha;
    }

    // P = exp2(S - m); 4-way partial sums (shorter dep chain than serial adds)
    float ls0 = 0.0f, ls1 = 0.0f, ls2 = 0.0f, ls3 = 0.0f;
    uint32_t pw[4][4];
#pragma unroll
    for (int kb = 0; kb < 2; kb++) {
      float p[16];
#pragma unroll
      for (int r = 0; r < 16; r += 4) {
        p[r + 0] = __builtin_amdgcn_exp2f(sc[kb][r + 0] - m_);
        p[r + 1] = __builtin_amdgcn_exp2f(sc[kb][r + 1] - m_);
        p[r + 2] = __builtin_amdgcn_exp2f(sc[kb][r + 2] - m_);
        p[r + 3] = __builtin_amdgcn_exp2f(sc[kb][r + 3] - m_);
        ls0 += p[r + 0]; ls1 += p[r + 1]; ls2 += p[r + 2]; ls3 += p[r + 3];
      }
#pragma unroll
      for (int ksl = 0; ksl < 2; ksl++) {
        const int fi = kb * 2 + ksl, b0 = ksl * 8;
        uint32_t a0 = cvtpk_bf16(p[b0 + 0], p[b0 + 1]);
        uint32_t b0w = cvtpk_bf16(p[b0 + 4], p[b0 + 5]);
        perm32swap(a0, b0w);
        uint32_t a1 = cvtpk_bf16(p[b0 + 2], p[b0 + 3]);
        uint32_t b1w = cvtpk_bf16(p[b0 + 6], p[b0 + 7]);
        perm32swap(a1, b1w);
        pw[fi][0] = a0; pw[fi][1] = a1; pw[fi][2] = b0w; pw[fi][3] = b1w;
      }
    }
    float ls = (ls0 + ls1) + (ls2 + ls3);
    ls += __shfl_xor(ls, 32);
    l_ += ls;

    __builtin_amdgcn_s_setprio(1);
#pragma unroll
    for (int db = 0; db < 2; db++) {
      const int d = db * 32 + l31;
#pragma unroll
      for (int ks = 0; ks < 4; ks++) {
        int ch = (2 * ks + hh) ^ (d & 7);
        s16x8 vf = *(const s16x8*)(VtS + cur * 4096 + d * 64 + ch * 8);
        i32x4 pv = {(int)pw[ks][0], (int)pw[ks][1], (int)pw[ks][2], (int)pw[ks][3]};
        oac[db] = MFMA32(vf, __builtin_bit_cast(s16x8, pv), oac[db]);
      }
    }
    __builtin_amdgcn_s_setprio(0);

    __syncthreads();
  }

  float* mrg = (float*)smem;
  float* ml  = mrg + 8192;
  if (half) {
#pragma unroll
    for (int db = 0; db < 2; db++)
#pragma unroll
      for (int r = 0; r < 16; r++)
        mrg[wq * 2048 + (db * 16 + r) * 64 + lane] = oac[db][r];
    ml[wq * 128 + lane * 2]     = m_;
    ml[wq * 128 + lane * 2 + 1] = l_;
  }
  __syncthreads();
  if (!half) {
    float m2 = ml[wq * 128 + lane * 2];
    float l2 = ml[wq * 128 + lane * 2 + 1];
    float mF = fmaxf(m_, m2);
    float e1 = __builtin_amdgcn_exp2f(m_ - mF);
    float e2 = __builtin_amdgcn_exp2f(m2 - mF);
    l_ = l_ * e1 + l2 * e2;
#pragma unroll
    for (int db = 0; db < 2; db++)
#pragma unroll
      for (int r = 0; r < 16; r++)
        oac[db][r] = oac[db][r] * e1 + mrg[wq * 2048 + (db * 16 + r) * 64 + lane] * e2;

    float inv = 1.0f / l_;
    short* epi = smem + 17408 + wq * 2048;
#pragma unroll
    for (int db = 0; db < 2; db++)
#pragma unroll
      for (int g = 0; g < 4; g++) {
        uint32_t w0 = cvtpk_bf16(oac[db][g * 4 + 0] * inv, oac[db][g * 4 + 1] * inv);
        uint32_t w1 = cvtpk_bf16(oac[db][g * 4 + 2] * inv, oac[db][g * 4 + 3] * inv);
        int chunk = db * 4 + g;
        uint2* dst = (uint2*)((char*)epi + l31 * 128 + ((chunk ^ (l31 & 7)) << 4) + hh * 8);
        *dst = make_uint2(w0, w1);
      }
#pragma unroll
    for (int i = 0; i < 4; i++) {
      int c = hh * 4 + i;
      s16x8 v = *(const s16x8*)((char*)epi + l31 * 128 + ((c ^ (l31 & 7)) << 4));
      *(s16x8*)(O + ((size_t)(b * 4096 + qrow) * 512) + h * 64 + c * 8) = v;
    }
  }
}

extern "C" void kernel_launch(void* const* d_in, const int* in_sizes, int n_in,
                              void* d_out, int out_size, void* d_ws, size_t ws_size,
                              hipStream_t stream) {
  const float* keys     = (const float*)d_in[0];
  const float* values   = (const float*)d_in[1];
  const uint32_t* maskp = (const uint32_t*)d_in[2];
  const float* qk_gamma = (const float*)d_in[3];
  const float* qk_beta  = (const float*)d_in[4];
  const float* v_gamma  = (const float*)d_in[5];
  const float* v_beta   = (const float*)d_in[6];
  const float* W_qk     = (const float*)d_in[7];
  const float* W_v      = (const float*)d_in[8];
  const float* W_out    = (const float*)d_in[9];
  const float* b_out    = (const float*)d_in[10];
  float* out = (float*)d_out;
  char* ws = (char*)d_ws;
  const size_t MB = 1u << 20;
  short* kn    = (short*)(ws);                     // 8193 rows x 512 bf16
  short* vn    = (short*)(ws + 9 * MB);
  short* Qg    = (short*)(ws + 18 * MB);
  short* Kg    = (short*)(ws + 26 * MB);
  short* VTg   = (short*)(ws + 34 * MB);
  short* O     = (short*)(ws + 42 * MB);
  short* WqkT  = (short*)(ws + 50 * MB);
  short* WvT   = (short*)(ws + 51 * MB);
  short* WoutT = (short*)(ws + 51 * MB + 512 * 1024);
  int*   idx   = (int*)(ws + 52 * MB);
  int*   cnts  = (int*)(ws + 52 * MB + 32 * 1024);

  prep_kernel<<<5123, 256, 0, stream>>>(maskp, W_qk, W_v, W_out, WqkT, WvT, WoutT,
                                        keys, values, qk_gamma, qk_beta, v_gamma, v_beta,
                                        kn, vn, idx, cnts);
  proj_kernel<<<1024, 256, 0, stream>>>(kn, vn, WqkT, WvT, idx, cnts, Qg, Kg, VTg);
  attn_kernel<<<512, 512, 0, stream>>>(Qg, Kg, VTg, cnts, O);
  gemm_out_kernel<<<dim3(64, 8), 256, 0, stream>>>(O, WoutT, b_out, out);
}